// Round 1
// baseline (45930.124 us; speedup 1.0000x reference)
//
#include <hip/hip_runtime.h>

// SimpleRNN: B=64,T=512,I=128,H=1024,L=4,O=128
// out[0..B*T*O)      = FC(out_layer3)
// out[B*T*O .. +LBH) = h_n [L,B,H]
#define B_ 64
#define T_ 512
#define I_ 128
#define H_ 1024
#define L_ 4
#define O_ 128
#define M_ (B_ * T_)   // 32768 rows for time-parallel GEMMs

typedef __attribute__((ext_vector_type(8))) short bf16x8_t;
typedef __attribute__((ext_vector_type(4))) float f32x4_t;

__device__ __forceinline__ unsigned short f2bf(float x) {
  // round-to-nearest-even fp32 -> bf16 (no NaN special-casing needed here)
  unsigned int u = __builtin_bit_cast(unsigned int, x);
  u += 0x7FFFu + ((u >> 16) & 1u);
  return (unsigned short)(u >> 16);
}
__device__ __forceinline__ float bf2f(unsigned short h) {
  return __builtin_bit_cast(float, ((unsigned int)h) << 16);
}
__device__ __forceinline__ f32x4_t mfma16(bf16x8_t a, bf16x8_t b, f32x4_t c) {
  return __builtin_amdgcn_mfma_f32_16x16x32_bf16(a, b, c, 0, 0, 0);
}

// ---------------------------------------------------------------------------
// Device-scope grid barrier (sense via generation counter).
// Safe: grid = 64 blocks << 256 CUs -> always co-resident. Counters zeroed by
// hipMemsetAsync at the start of every kernel_launch (ws is re-poisoned).
// ---------------------------------------------------------------------------
__device__ __forceinline__ void grid_bar(unsigned* cnt, unsigned* gen, unsigned nb) {
  __threadfence();        // release my writes (device scope, wb L2)
  __syncthreads();
  if (threadIdx.x == 0) {
    unsigned g = __hip_atomic_load(gen, __ATOMIC_RELAXED, __HIP_MEMORY_SCOPE_AGENT);
    unsigned old = __hip_atomic_fetch_add(cnt, 1u, __ATOMIC_ACQ_REL, __HIP_MEMORY_SCOPE_AGENT);
    if (old == nb - 1u) {
      __hip_atomic_store(cnt, 0u, __ATOMIC_RELAXED, __HIP_MEMORY_SCOPE_AGENT);
      __hip_atomic_store(gen, g + 1u, __ATOMIC_RELEASE, __HIP_MEMORY_SCOPE_AGENT);
    } else {
      while (__hip_atomic_load(gen, __ATOMIC_RELAXED, __HIP_MEMORY_SCOPE_AGENT) == g) {
        __builtin_amdgcn_s_sleep(2);
      }
    }
  }
  __syncthreads();
  __threadfence();        // acquire: invalidate caches before reading peers' data
}

// ---------------------------------------------------------------------------
// Generic MFMA GEMM: C[M_,N] = A[M_,K] @ W[N,K]^T + bias1 + bias2
// Split-bf16: W converted to hi/lo during staging (exact to ~2^-16).
// ASPLIT: A is fp32 and also split hi/lo (3 MFMA terms), else A is bf16 (2 terms).
// Block tile 128x128, 4 waves (2x2), wave tile 64x64, BK=64.
// LDS tiles stored in MFMA-fragment order -> aligned, ~conflict-free ds_read_b128.
// ---------------------------------------------------------------------------
template <int K, int N, bool ASPLIT, bool OUTBF16>
__global__ __launch_bounds__(256, 2) void gemm_k(
    const void* __restrict__ Aq, const float* __restrict__ Wf,
    const float* __restrict__ bias1, const float* __restrict__ bias2,
    void* __restrict__ Cq) {
  extern __shared__ unsigned short smem[];
  unsigned short* Ahi = smem;                          // 8192 shorts
  unsigned short* Alo = Ahi + (ASPLIT ? 8192 : 0);     // aliases Ahi if !ASPLIT
  unsigned short* Bhi = Alo + 8192;
  unsigned short* Blo = Bhi + 8192;

  const int tid = threadIdx.x;
  const int wave = tid >> 6, lane = tid & 63;
  const int wm = wave >> 1, wn = wave & 1;
  const int lm = lane & 15, lk = lane >> 4;
  const int m0 = blockIdx.y * 128, n0 = blockIdx.x * 128;

  f32x4_t acc[4][4] = {};

  for (int kc = 0; kc < K; kc += 64) {
    __syncthreads();
    // ---- stage A tile (128 rows x 64 k) in frag order: idx = ((kit*4+ko)*128+row)*8
#pragma unroll
    for (int p = 0; p < 4; ++p) {
      int fl = p * 256 + tid;
      int row = fl & 127, ko = (fl >> 7) & 3, kit = fl >> 9;
      int kk = kc + kit * 32 + ko * 8;
      if (ASPLIT) {
        const float* src = (const float*)Aq + (size_t)(m0 + row) * K + kk;
        union { bf16x8_t s; unsigned short u[8]; } th, tl;
#pragma unroll
        for (int e = 0; e < 8; ++e) {
          float v = src[e];
          unsigned short h = f2bf(v);
          th.u[e] = (short)h;
          tl.u[e] = (short)f2bf(v - bf2f(h));
        }
        *(bf16x8_t*)(Ahi + (size_t)fl * 8) = th.s;
        *(bf16x8_t*)(Alo + (size_t)fl * 8) = tl.s;
      } else {
        const unsigned short* src = (const unsigned short*)Aq + (size_t)(m0 + row) * K + kk;
        *(bf16x8_t*)(Ahi + (size_t)fl * 8) = *(const bf16x8_t*)src;
      }
    }
    // ---- stage B tile (128 neuron rows x 64 k), fp32 -> hi/lo
#pragma unroll
    for (int p = 0; p < 4; ++p) {
      int fl = p * 256 + tid;
      int row = fl & 127, ko = (fl >> 7) & 3, kit = fl >> 9;
      int kk = kc + kit * 32 + ko * 8;
      const float* src = Wf + (size_t)(n0 + row) * K + kk;
      union { bf16x8_t s; unsigned short u[8]; } th, tl;
#pragma unroll
      for (int e = 0; e < 8; ++e) {
        float v = src[e];
        unsigned short h = f2bf(v);
        th.u[e] = (short)h;
        tl.u[e] = (short)f2bf(v - bf2f(h));
      }
      *(bf16x8_t*)(Bhi + (size_t)fl * 8) = th.s;
      *(bf16x8_t*)(Blo + (size_t)fl * 8) = tl.s;
    }
    __syncthreads();
    // ---- compute
#pragma unroll
    for (int kit = 0; kit < 2; ++kit) {
      bf16x8_t bh[4], bl4[4];
#pragma unroll
      for (int n = 0; n < 4; ++n) {
        int br = wn * 64 + n * 16 + lm;
        bh[n] = *(const bf16x8_t*)(Bhi + ((size_t)(kit * 4 + lk) * 128 + br) * 8);
        bl4[n] = *(const bf16x8_t*)(Blo + ((size_t)(kit * 4 + lk) * 128 + br) * 8);
      }
#pragma unroll
      for (int m = 0; m < 4; ++m) {
        int ar = wm * 64 + m * 16 + lm;
        bf16x8_t a = *(const bf16x8_t*)(Ahi + ((size_t)(kit * 4 + lk) * 128 + ar) * 8);
        bf16x8_t al;
        if (ASPLIT) al = *(const bf16x8_t*)(Alo + ((size_t)(kit * 4 + lk) * 128 + ar) * 8);
#pragma unroll
        for (int n = 0; n < 4; ++n) {
          acc[m][n] = mfma16(a, bh[n], acc[m][n]);
          acc[m][n] = mfma16(a, bl4[n], acc[m][n]);
          if (ASPLIT) acc[m][n] = mfma16(al, bh[n], acc[m][n]);
        }
      }
    }
  }

  // ---- epilogue: D lane map row=(lane>>4)*4+r, col=lane&15
#pragma unroll
  for (int n = 0; n < 4; ++n) {
    int col = n0 + wn * 64 + n * 16 + lm;
    float bv = bias1[col];
    if (bias2 != nullptr) bv += bias2[col];
#pragma unroll
    for (int m = 0; m < 4; ++m) {
#pragma unroll
      for (int r = 0; r < 4; ++r) {
        int row = m0 + wm * 64 + m * 16 + lk * 4 + r;
        float v = acc[m][n][r] + bv;
        if (OUTBF16)
          ((unsigned short*)Cq)[(size_t)row * N + col] = f2bf(v);
        else
          ((float*)Cq)[(size_t)row * N + col] = v;
      }
    }
  }
}

// ---------------------------------------------------------------------------
// Persistent recurrence kernel for one layer.
// 64 blocks x 256 thr; block owns 16 neurons; wave w owns batches 16w..16w+15.
// Whh slice kept in ~256 VGPRs as pre-split B-fragments for all 512 steps.
// h state: 2-slot global ring in frag order [slot][kit][ko][b][8], hi+lo.
// h_t = relu(xin[:,t,:] + h_{t-1} @ Whh^T), split-bf16 (3 MFMA terms).
// ---------------------------------------------------------------------------
__global__ __launch_bounds__(256, 1) void rec_k(
    const unsigned short* __restrict__ xin,  // [M_,H] bf16, biases included
    const float* __restrict__ h0,            // hidden[l]: [B_,H]
    const float* __restrict__ Whh,           // [H,H] fp32
    unsigned short* __restrict__ seq,        // [M_,H] bf16 out (= layer output, hi)
    float* __restrict__ hn,                  // d_out + B*T*O + l*B*H
    unsigned short* __restrict__ ringHi,     // [2][32][4][64][8]
    unsigned short* __restrict__ ringLo,
    unsigned* __restrict__ barc, unsigned* __restrict__ barg) {
  const int tid = threadIdx.x;
  const int wave = tid >> 6, lane = tid & 63;
  const int lm = lane & 15, lk = lane >> 4;
  const int wb = wave * 16;            // batch base of this wave
  const int j0 = blockIdx.x * 16;      // neuron base of this block
  const unsigned nb = gridDim.x;

  // ---- load Whh B-frags into registers (hi/lo), once
  bf16x8_t bh[32], bl[32];
#pragma unroll
  for (int kit = 0; kit < 32; ++kit) {
    const float* src = Whh + (size_t)(j0 + lm) * H_ + kit * 32 + lk * 8;
    union { bf16x8_t s; unsigned short u[8]; } th, tl;
#pragma unroll
    for (int e = 0; e < 8; ++e) {
      float v = src[e];
      unsigned short h = f2bf(v);
      th.u[e] = (short)h;
      tl.u[e] = (short)f2bf(v - bf2f(h));
    }
    bh[kit] = th.s;
    bl[kit] = tl.s;
  }

  // ---- init ring slot 1 with h0 (t=0 reads slot (0+1)&1 = 1)
  {
    int base = (blockIdx.x * 256 + tid) * 4;  // 16384 threads * 4 = 65536 = B_*H_
#pragma unroll
    for (int e = 0; e < 4; ++e) {
      int idx = base + e;
      int b = idx >> 10, k = idx & 1023;
      float v = h0[idx];
      unsigned short hi = f2bf(v), lo = f2bf(v - bf2f(hi));
      int pos = 65536 + ((k >> 5) * 4 + ((k >> 3) & 3)) * 512 + b * 8 + (k & 7);
      ringHi[pos] = hi;
      ringLo[pos] = lo;
    }
  }
  grid_bar(barc, barg, nb);

  for (int t = 0; t < T_; ++t) {
    const int sr = (((t & 1) ^ 1)) * 65536;  // read slot
    const int sw = (t & 1) * 65536;          // write slot
    f32x4_t acc = {0.f, 0.f, 0.f, 0.f};
#pragma unroll
    for (int kit = 0; kit < 32; ++kit) {
      const int p = sr + kit * 2048 + lk * 512 + (wb + lm) * 8;
      bf16x8_t ah = *(const bf16x8_t*)(ringHi + p);
      bf16x8_t al = *(const bf16x8_t*)(ringLo + p);
      acc = mfma16(ah, bh[kit], acc);
      acc = mfma16(al, bh[kit], acc);
      acc = mfma16(ah, bl[kit], acc);
    }
    const int j = j0 + lm;
#pragma unroll
    for (int r = 0; r < 4; ++r) {
      const int b = wb + lk * 4 + r;
      float v = acc[r] + bf2f(xin[(size_t)(b * T_ + t) * H_ + j]);
      v = fmaxf(v, 0.f);
      unsigned short hi = f2bf(v), lo = f2bf(v - bf2f(hi));
      int pos = sw + ((j >> 5) * 4 + ((j >> 3) & 3)) * 512 + b * 8 + (j & 7);
      ringHi[pos] = hi;
      ringLo[pos] = lo;
      seq[(size_t)(b * T_ + t) * H_ + j] = hi;
      if (t == T_ - 1) hn[b * H_ + j] = v;
    }
    grid_bar(barc, barg, nb);
  }
}

// ---------------------------------------------------------------------------
// kernel_launch: 10 nodes, all graph-capture-safe.
// ws layout: [0,1024) barrier | xin 64MB bf16 | seq 64MB bf16 | ring 512KB
// total ~128.5 MB.
// ---------------------------------------------------------------------------
extern "C" void kernel_launch(void* const* d_in, const int* in_sizes, int n_in,
                              void* d_out, int out_size, void* d_ws, size_t ws_size,
                              hipStream_t stream) {
  const float* x = (const float*)d_in[0];
  const float* hidden = (const float*)d_in[1];
  const float* Wih0 = (const float*)d_in[2];
  const float* Whh0 = (const float*)d_in[3];
  const float* bih0 = (const float*)d_in[4];
  const float* bhh0 = (const float*)d_in[5];
  const float* WihL = (const float*)d_in[6];
  const float* WhhL = (const float*)d_in[7];
  const float* bihL = (const float*)d_in[8];
  const float* bhhL = (const float*)d_in[9];
  const float* Wfc = (const float*)d_in[10];
  const float* bfc = (const float*)d_in[11];
  float* out = (float*)d_out;
  float* hn = out + (size_t)M_ * O_;

  char* ws = (char*)d_ws;
  unsigned* barc = (unsigned*)ws;
  unsigned* barg = barc + 1;
  unsigned short* xin = (unsigned short*)(ws + 1024);
  unsigned short* seq = xin + (size_t)M_ * H_;
  unsigned short* ringHi = seq + (size_t)M_ * H_;
  unsigned short* ringLo = ringHi + 2 * B_ * H_;

  hipMemsetAsync(ws, 0, 1024, stream);  // barrier counters

  for (int l = 0; l < L_; ++l) {
    if (l == 0) {
      gemm_k<I_, H_, true, true><<<dim3(H_ / 128, M_ / 128), 256, 64 * 1024, stream>>>(
          (const void*)x, Wih0, bih0, bhh0, (void*)xin);
    } else {
      gemm_k<H_, H_, false, true><<<dim3(H_ / 128, M_ / 128), 256, 48 * 1024, stream>>>(
          (const void*)seq, WihL + (size_t)(l - 1) * H_ * H_,
          bihL + (size_t)(l - 1) * H_, bhhL + (size_t)(l - 1) * H_, (void*)xin);
    }
    const float* Whh = (l == 0) ? Whh0 : WhhL + (size_t)(l - 1) * H_ * H_;
    rec_k<<<64, 256, 0, stream>>>(xin, hidden + (size_t)l * B_ * H_, Whh, seq,
                                  hn + (size_t)l * B_ * H_, ringHi, ringLo, barc, barg);
  }
  // FC: out = seq @ Wfc^T + bfc
  gemm_k<H_, O_, false, false><<<dim3(O_ / 128, M_ / 128), 256, 48 * 1024, stream>>>(
      (const void*)seq, Wfc, bfc, nullptr, (void*)out);
}

// Round 2
// 6247.322 us; speedup vs baseline: 7.3520x; 7.3520x over previous
//
#include <hip/hip_runtime.h>

// SimpleRNN: B=64,T=512,I=128,H=1024,L=4,O=128
// Round 2: single persistent pipelined kernel (4 layers concurrent),
// relaxed agent-scope atomics for all cross-block data (no fences),
// per-(layer,batchgroup) 16-block barriers.
#define B_ 64
#define T_ 512
#define I_ 128
#define H_ 1024
#define L_ 4
#define O_ 128
#define M_ (B_ * T_)
#define D_ 32   // inter-layer seq ring depth (steps)

typedef __attribute__((ext_vector_type(8))) short bf16x8_t;
typedef __attribute__((ext_vector_type(4))) float f32x4_t;

__device__ __forceinline__ unsigned short f2bf(float x) {
  unsigned int u = __builtin_bit_cast(unsigned int, x);
  u += 0x7FFFu + ((u >> 16) & 1u);
  return (unsigned short)(u >> 16);
}
__device__ __forceinline__ float bf2f(unsigned short h) {
  return __builtin_bit_cast(float, ((unsigned int)h) << 16);
}
__device__ __forceinline__ f32x4_t mfma16(bf16x8_t a, bf16x8_t b, f32x4_t c) {
  return __builtin_amdgcn_mfma_f32_16x16x32_bf16(a, b, c, 0, 0, 0);
}

// Relaxed agent-scope atomics: performed at the device coherence point
// (bypass per-XCD L2) -> cross-XCD visible without wbl2/inv fences.
__device__ __forceinline__ unsigned aldc(const unsigned* p) {
  return __hip_atomic_load(p, __ATOMIC_RELAXED, __HIP_MEMORY_SCOPE_AGENT);
}
__device__ __forceinline__ unsigned long long ald64(const unsigned long long* p) {
  return __hip_atomic_load(p, __ATOMIC_RELAXED, __HIP_MEMORY_SCOPE_AGENT);
}
__device__ __forceinline__ void ast32(unsigned* p, unsigned v) {
  __hip_atomic_store(p, v, __ATOMIC_RELAXED, __HIP_MEMORY_SCOPE_AGENT);
}

// ---------------------------------------------------------------------------
// Generic MFMA GEMM (round-1, proven): C[M_,N] = A[M_,K] @ W[N,K]^T + bias
// Used only for the final FC here.
// ---------------------------------------------------------------------------
template <int K, int N, bool ASPLIT, bool OUTBF16>
__global__ __launch_bounds__(256, 2) void gemm_k(
    const void* __restrict__ Aq, const float* __restrict__ Wf,
    const float* __restrict__ bias1, const float* __restrict__ bias2,
    void* __restrict__ Cq) {
  extern __shared__ unsigned short smem[];
  unsigned short* Ahi = smem;
  unsigned short* Alo = Ahi + (ASPLIT ? 8192 : 0);
  unsigned short* Bhi = Alo + 8192;
  unsigned short* Blo = Bhi + 8192;

  const int tid = threadIdx.x;
  const int wave = tid >> 6, lane = tid & 63;
  const int wm = wave >> 1, wn = wave & 1;
  const int lm = lane & 15, lk = lane >> 4;
  const int m0 = blockIdx.y * 128, n0 = blockIdx.x * 128;

  f32x4_t acc[4][4] = {};

  for (int kc = 0; kc < K; kc += 64) {
    __syncthreads();
#pragma unroll
    for (int p = 0; p < 4; ++p) {
      int fl = p * 256 + tid;
      int row = fl & 127, ko = (fl >> 7) & 3, kit = fl >> 9;
      int kk = kc + kit * 32 + ko * 8;
      if (ASPLIT) {
        const float* src = (const float*)Aq + (size_t)(m0 + row) * K + kk;
        union { bf16x8_t s; unsigned short u[8]; } th, tl;
#pragma unroll
        for (int e = 0; e < 8; ++e) {
          float v = src[e];
          unsigned short h = f2bf(v);
          th.u[e] = (short)h;
          tl.u[e] = (short)f2bf(v - bf2f(h));
        }
        *(bf16x8_t*)(Ahi + (size_t)fl * 8) = th.s;
        *(bf16x8_t*)(Alo + (size_t)fl * 8) = tl.s;
      } else {
        const unsigned short* src = (const unsigned short*)Aq + (size_t)(m0 + row) * K + kk;
        *(bf16x8_t*)(Ahi + (size_t)fl * 8) = *(const bf16x8_t*)src;
      }
    }
#pragma unroll
    for (int p = 0; p < 4; ++p) {
      int fl = p * 256 + tid;
      int row = fl & 127, ko = (fl >> 7) & 3, kit = fl >> 9;
      int kk = kc + kit * 32 + ko * 8;
      const float* src = Wf + (size_t)(n0 + row) * K + kk;
      union { bf16x8_t s; unsigned short u[8]; } th, tl;
#pragma unroll
      for (int e = 0; e < 8; ++e) {
        float v = src[e];
        unsigned short h = f2bf(v);
        th.u[e] = (short)h;
        tl.u[e] = (short)f2bf(v - bf2f(h));
      }
      *(bf16x8_t*)(Bhi + (size_t)fl * 8) = th.s;
      *(bf16x8_t*)(Blo + (size_t)fl * 8) = tl.s;
    }
    __syncthreads();
#pragma unroll
    for (int kit = 0; kit < 2; ++kit) {
      bf16x8_t bhf[4], blf[4];
#pragma unroll
      for (int n = 0; n < 4; ++n) {
        int br = wn * 64 + n * 16 + lm;
        bhf[n] = *(const bf16x8_t*)(Bhi + ((size_t)(kit * 4 + lk) * 128 + br) * 8);
        blf[n] = *(const bf16x8_t*)(Blo + ((size_t)(kit * 4 + lk) * 128 + br) * 8);
      }
#pragma unroll
      for (int m = 0; m < 4; ++m) {
        int ar = wm * 64 + m * 16 + lm;
        bf16x8_t a = *(const bf16x8_t*)(Ahi + ((size_t)(kit * 4 + lk) * 128 + ar) * 8);
        bf16x8_t al;
        if (ASPLIT) al = *(const bf16x8_t*)(Alo + ((size_t)(kit * 4 + lk) * 128 + ar) * 8);
#pragma unroll
        for (int n = 0; n < 4; ++n) {
          acc[m][n] = mfma16(a, bhf[n], acc[m][n]);
          acc[m][n] = mfma16(a, blf[n], acc[m][n]);
          if (ASPLIT) acc[m][n] = mfma16(al, bhf[n], acc[m][n]);
        }
      }
    }
  }
#pragma unroll
  for (int n = 0; n < 4; ++n) {
    int col = n0 + wn * 64 + n * 16 + lm;
    float bv = bias1[col];
    if (bias2 != nullptr) bv += bias2[col];
#pragma unroll
    for (int m = 0; m < 4; ++m) {
#pragma unroll
      for (int r = 0; r < 4; ++r) {
        int row = m0 + wm * 64 + m * 16 + lk * 4 + r;
        float v = acc[m][n][r] + bv;
        if (OUTBF16)
          ((unsigned short*)Cq)[(size_t)row * N + col] = f2bf(v);
        else
          ((float*)Cq)[(size_t)row * N + col] = v;
      }
    }
  }
}

// ---------------------------------------------------------------------------
// x pre-split: fp32 -> (hi, lo) bf16 planes, same flat [B,T,I] layout.
// ---------------------------------------------------------------------------
__global__ __launch_bounds__(256) void splitx_k(const float* __restrict__ x,
                                               unsigned short* __restrict__ xhi,
                                               unsigned short* __restrict__ xlo) {
  int i = (blockIdx.x * 256 + threadIdx.x) * 4;
  float4 v = *(const float4*)(x + i);
  ushort4 h, lo;
  h.x = f2bf(v.x); lo.x = f2bf(v.x - bf2f(h.x));
  h.y = f2bf(v.y); lo.y = f2bf(v.y - bf2f(h.y));
  h.z = f2bf(v.z); lo.z = f2bf(v.z - bf2f(h.z));
  h.w = f2bf(v.w); lo.w = f2bf(v.w - bf2f(h.w));
  *(ushort4*)(xhi + i) = h;
  *(ushort4*)(xlo + i) = lo;
}

// ---------------------------------------------------------------------------
// Persistent pipelined RNN. Grid = 256 blocks: block = (layer l = bid>>6,
// ngB = (bid&63)>>2, bg = bid&3). Block: 64 neurons (4 waves x 16) x 16
// batches. Whh hi/lo (+Wih hi) B-frags live in registers for all 512 steps.
// h ring + seq ring in global, frag-order per (bg)-slice, accessed with
// relaxed agent atomics; per-(l,bg) monotonic arrive counters (16 blocks).
// Step t: read h slot (t&1)^1, write slot t&1. cnt >= 16*(t+1) <=> group
// finished step t-1 (init counts as step -1).
// ---------------------------------------------------------------------------
template <bool L0>
__device__ void run_layer(int l, int bg, int j0, int tid, int lm, int lk,
                          const float* __restrict__ Whh, const float* __restrict__ Wih,
                          float bias,
                          const unsigned short* __restrict__ xhi,
                          const unsigned short* __restrict__ xlo,
                          unsigned* __restrict__ ring, unsigned short* __restrict__ seqr,
                          unsigned short* __restrict__ s3, float* __restrict__ hn,
                          unsigned* __restrict__ cnt, unsigned short* __restrict__ lds) {
  const int j = j0 + lm;

  // ---- Whh B-frags (hi/lo) in registers
  bf16x8_t bh[32], bl[32];
#pragma unroll
  for (int kit = 0; kit < 32; ++kit) {
    const float* src = Whh + (size_t)j * H_ + kit * 32 + lk * 8;
    union { bf16x8_t s; unsigned short u[8]; } th, tl;
#pragma unroll
    for (int e = 0; e < 8; ++e) {
      float v = src[e];
      unsigned short h = f2bf(v);
      th.u[e] = (short)h;
      tl.u[e] = (short)f2bf(v - bf2f(h));
    }
    bh[kit] = th.s; bl[kit] = tl.s;
  }
  // ---- Wih B-frags: layers 1-3: hi only, K=1024; layer 0: hi/lo, K=128
  bf16x8_t bw[32];
  bf16x8_t w0h[4], w0l[4];
  if constexpr (!L0) {
#pragma unroll
    for (int kit = 0; kit < 32; ++kit) {
      const float* src = Wih + (size_t)j * H_ + kit * 32 + lk * 8;
      union { bf16x8_t s; unsigned short u[8]; } th;
#pragma unroll
      for (int e = 0; e < 8; ++e) th.u[e] = (short)f2bf(src[e]);
      bw[kit] = th.s;
    }
  } else {
#pragma unroll
    for (int kit = 0; kit < 4; ++kit) {
      const float* src = Wih + (size_t)j * I_ + kit * 32 + lk * 8;
      union { bf16x8_t s; unsigned short u[8]; } th, tl;
#pragma unroll
      for (int e = 0; e < 8; ++e) {
        float v = src[e];
        unsigned short h = f2bf(v);
        th.u[e] = (short)h;
        tl.u[e] = (short)f2bf(v - bf2f(h));
      }
      w0h[kit] = th.s; w0l[kit] = tl.s;
    }
  }

  unsigned* cown = cnt + (l * 4 + bg) * 64;
  unsigned* cup = cnt + ((l - 1) * 4 + bg) * 64;
  unsigned* cdn = cnt + ((l + 1) * 4 + bg) * 64;
  const bool hasDn = (l < 3);
  const int kitJ = j >> 5, lkJ = (j >> 3) & 3, eJ = j & 7;

  for (int t = 0; t < T_; ++t) {
    if (tid == 0) {
      while (aldc(cown) < 16u * (unsigned)(t + 1)) __builtin_amdgcn_s_sleep(1);
      if constexpr (!L0) {
        while (aldc(cup) < 16u * (unsigned)(t + 2)) __builtin_amdgcn_s_sleep(1);
      }
      if (hasDn && t >= D_) {
        while (aldc(cdn) < 16u * (unsigned)(t - D_ + 2)) __builtin_amdgcn_s_sleep(1);
      }
    }
    asm volatile("" ::: "memory");
    __syncthreads();

    // ---- stage h ring slice (64 KB u32 hi|lo) -> LDS hi/lo planes
    {
      const unsigned long long* rs64 =
          (const unsigned long long*)(ring + ((size_t)(l * 2 + ((t & 1) ^ 1)) * 4 + bg) * 16384);
      unsigned long long tmp[32];
#pragma unroll
      for (int i = 0; i < 32; ++i) tmp[i] = ald64(rs64 + i * 256 + tid);
#pragma unroll
      for (int i = 0; i < 32; ++i) {
        unsigned w0 = (unsigned)tmp[i], w1 = (unsigned)(tmp[i] >> 32);
        ((unsigned*)lds)[i * 256 + tid] = (w0 & 0xFFFFu) | (w1 << 16);
        ((unsigned*)(lds + 16384))[i * 256 + tid] = (w0 >> 16) | (w1 & 0xFFFF0000u);
      }
    }
    // ---- stage upstream seq slice (32 KB bf16) -> LDS
    if constexpr (!L0) {
      const unsigned long long* ss64 =
          (const unsigned long long*)(seqr + ((size_t)((l - 1) * D_ + (t & (D_ - 1))) * 4 + bg) * 16384);
      unsigned long long tmp[16];
#pragma unroll
      for (int i = 0; i < 16; ++i) tmp[i] = ald64(ss64 + i * 256 + tid);
      unsigned long long* dst = (unsigned long long*)(lds + 32768);
#pragma unroll
      for (int i = 0; i < 16; ++i) dst[i * 256 + tid] = tmp[i];
    }
    __syncthreads();

    // ---- MFMA: 4 independent acc chains
    f32x4_t a0 = {0.f, 0.f, 0.f, 0.f}, a1 = a0, a2 = a0, a3 = a0;
    const char* ldsb = (const char*)lds;
#pragma unroll
    for (int kit = 0; kit < 32; ++kit) {
      const int fo = ((kit * 4 + lk) * 16 + lm) * 16;
      bf16x8_t ah = *(const bf16x8_t*)(ldsb + fo);
      bf16x8_t al = *(const bf16x8_t*)(ldsb + 32768 + fo);
      a0 = mfma16(ah, bh[kit], a0);
      a1 = mfma16(al, bh[kit], a1);
      a2 = mfma16(ah, bl[kit], a2);
      if constexpr (!L0) {
        bf16x8_t as = *(const bf16x8_t*)(ldsb + 65536 + fo);
        a3 = mfma16(as, bw[kit], a3);
      }
    }
    if constexpr (L0) {
      const int b = bg * 16 + lm;
#pragma unroll
      for (int kit = 0; kit < 4; ++kit) {
        const size_t xo = ((size_t)b * T_ + t) * I_ + kit * 32 + lk * 8;
        bf16x8_t xh = *(const bf16x8_t*)(xhi + xo);
        bf16x8_t xl = *(const bf16x8_t*)(xlo + xo);
        a3 = mfma16(xh, w0h[kit], a3);
        a3 = mfma16(xl, w0h[kit], a3);
        a3 = mfma16(xh, w0l[kit], a3);
      }
    }

    // ---- epilogue: lane holds (j, b = bg*16 + lk*4 + r)
    unsigned* rw = ring + ((size_t)(l * 2 + (t & 1)) * 4 + bg) * 16384;
    unsigned* sw = (unsigned*)(seqr + ((size_t)(l * D_ + (t & (D_ - 1))) * 4 + bg) * 16384);
#pragma unroll
    for (int r = 0; r < 4; ++r) {
      const int b15 = lk * 4 + r;
      float v = a0[r] + a1[r] + a2[r] + a3[r] + bias;
      v = fmaxf(v, 0.f);
      unsigned hi = f2bf(v);
      unsigned lo = f2bf(v - bf2f((unsigned short)hi));
      const int idx = ((kitJ * 4 + lkJ) * 16 + b15) * 8 + eJ;
      ast32(rw + idx, hi | (lo << 16));
      int other = __shfl_xor((int)hi, 1);  // pair (j even, j odd) within wave
      if (l < 3) {
        if (!(lm & 1)) ast32(sw + (idx >> 1), hi | ((unsigned)other << 16));
      } else {
        s3[((size_t)(bg * 16 + b15) * T_ + t) * H_ + j] = (unsigned short)hi;
      }
      if (t == T_ - 1) hn[(size_t)l * B_ * H_ + (bg * 16 + b15) * H_ + j] = v;
    }
    __syncthreads();
    if (tid == 0)
      __hip_atomic_fetch_add(cown, 1u, __ATOMIC_RELEASE, __HIP_MEMORY_SCOPE_AGENT);
  }
}

__global__ __launch_bounds__(256, 1) void rnn_k(
    const float* __restrict__ hidden,
    const float* __restrict__ Wih0, const float* __restrict__ Whh0,
    const float* __restrict__ bih0, const float* __restrict__ bhh0,
    const float* __restrict__ WihL, const float* __restrict__ WhhL,
    const float* __restrict__ bihL, const float* __restrict__ bhhL,
    const unsigned short* __restrict__ xhi, const unsigned short* __restrict__ xlo,
    unsigned* __restrict__ ring, unsigned short* __restrict__ seqr,
    unsigned short* __restrict__ s3, float* __restrict__ hn,
    unsigned* __restrict__ cnt) {
  extern __shared__ unsigned char ldsraw[];  // 96 KB: hi 32K | lo 32K | seq 32K
  unsigned short* lds = (unsigned short*)ldsraw;
  const int tid = threadIdx.x;
  const int wave = tid >> 6, lane = tid & 63;
  const int lm = lane & 15, lk = lane >> 4;
  const int l = blockIdx.x >> 6;
  const int sub = blockIdx.x & 63;
  const int ngB = sub >> 2, bg = sub & 3;
  const int j0 = ngB * 64 + wave * 16;
  const int j = j0 + lm;
  unsigned* cown = cnt + (l * 4 + bg) * 64;

  // ---- init h ring slot 1 with hidden[l] (counts as "step -1")
  {
    unsigned* rsl = ring + ((size_t)(l * 2 + 1) * 4 + bg) * 16384;
#pragma unroll
    for (int v4 = 0; v4 < 4; ++v4) {
      int idx = tid + 256 * v4;
      int b16 = idx & 15, jj = idx >> 4;
      int jx = ngB * 64 + jj;
      float hv = hidden[(size_t)l * B_ * H_ + (bg * 16 + b16) * H_ + jx];
      unsigned short hi = f2bf(hv);
      unsigned short lo = f2bf(hv - bf2f(hi));
      ast32(rsl + (((jx >> 5) * 4 + ((jx >> 3) & 3)) * 16 + b16) * 8 + (jx & 7),
            (unsigned)hi | ((unsigned)lo << 16));
    }
  }
  __syncthreads();
  if (tid == 0)
    __hip_atomic_fetch_add(cown, 1u, __ATOMIC_RELEASE, __HIP_MEMORY_SCOPE_AGENT);

  float bias;
  if (l == 0) bias = bih0[j] + bhh0[j];
  else bias = bihL[(size_t)(l - 1) * H_ + j] + bhhL[(size_t)(l - 1) * H_ + j];

  if (l == 0)
    run_layer<true>(l, bg, j0, tid, lm, lk, Whh0, Wih0, bias, xhi, xlo,
                    ring, seqr, s3, hn, cnt, lds);
  else
    run_layer<false>(l, bg, j0, tid, lm, lk,
                     WhhL + (size_t)(l - 1) * H_ * H_, WihL + (size_t)(l - 1) * H_ * H_,
                     bias, xhi, xlo, ring, seqr, s3, hn, cnt, lds);
}

// ---------------------------------------------------------------------------
// ws layout: cnt 4 KB | ring 2 MB (u32 hi|lo, [l][slot2][bg][16384]) |
// seqr 12 MB (u16, [l0..2][D_][bg][16384]) | s3 64 MB (bf16 [M,H]) |
// xhi 8 MB | xlo 8 MB  => ~94 MB total.
// ---------------------------------------------------------------------------
extern "C" void kernel_launch(void* const* d_in, const int* in_sizes, int n_in,
                              void* d_out, int out_size, void* d_ws, size_t ws_size,
                              hipStream_t stream) {
  const float* x = (const float*)d_in[0];
  const float* hidden = (const float*)d_in[1];
  const float* Wih0 = (const float*)d_in[2];
  const float* Whh0 = (const float*)d_in[3];
  const float* bih0 = (const float*)d_in[4];
  const float* bhh0 = (const float*)d_in[5];
  const float* WihL = (const float*)d_in[6];
  const float* WhhL = (const float*)d_in[7];
  const float* bihL = (const float*)d_in[8];
  const float* bhhL = (const float*)d_in[9];
  const float* Wfc = (const float*)d_in[10];
  const float* bfc = (const float*)d_in[11];
  float* out = (float*)d_out;
  float* hn = out + (size_t)M_ * O_;

  char* ws = (char*)d_ws;
  unsigned* cnt = (unsigned*)ws;
  unsigned* ring = (unsigned*)(ws + 4096);
  unsigned short* seqr = (unsigned short*)(ws + 4096 + (2u << 20));
  unsigned short* s3 = (unsigned short*)(ws + 4096 + (2u << 20) + (12u << 20));
  unsigned short* xhi = (unsigned short*)(ws + 4096 + (2u << 20) + (12u << 20) + (64u << 20));
  unsigned short* xlo = xhi + (size_t)B_ * T_ * I_;

  hipMemsetAsync(ws, 0, 4096, stream);  // arrive counters
  splitx_k<<<(B_ * T_ * I_) / 1024, 256, 0, stream>>>(x, xhi, xlo);

  hipFuncSetAttribute((const void*)rnn_k, hipFuncAttributeMaxDynamicSharedMemorySize,
                      96 * 1024);
  rnn_k<<<256, 256, 96 * 1024, stream>>>(hidden, Wih0, Whh0, bih0, bhh0,
                                         WihL, WhhL, bihL, bhhL, xhi, xlo,
                                         ring, seqr, s3, hn, cnt);

  gemm_k<H_, O_, false, false><<<dim3(O_ / 128, M_ / 128), 256, 48 * 1024, stream>>>(
      (const void*)s3, Wfc, bfc, nullptr, (void*)out);
}

// Round 4
// 2332.696 us; speedup vs baseline: 19.6897x; 2.6782x over previous
//
#include <hip/hip_runtime.h>

// SimpleRNN: B=64,T=512,I=128,H=1024,L=4,O=128
// Round 4: round-2 proven skeleton (pure HIP atomics, sc1/IC transport) +
// per-block release counters w/ ballot polls + hi-only h/Whh (half traffic).
#define B_ 64
#define T_ 512
#define I_ 128
#define H_ 1024
#define L_ 4
#define O_ 128
#define M_ (B_ * T_)
#define D_ 32  // inter-layer seq ring depth (steps)

typedef __attribute__((ext_vector_type(8))) short bf16x8_t;
typedef __attribute__((ext_vector_type(4))) float f32x4_t;

__device__ __forceinline__ unsigned short f2bf(float x) {
  unsigned int u = __builtin_bit_cast(unsigned int, x);
  u += 0x7FFFu + ((u >> 16) & 1u);
  return (unsigned short)(u >> 16);
}
__device__ __forceinline__ float bf2f(unsigned short h) {
  return __builtin_bit_cast(float, ((unsigned int)h) << 16);
}
__device__ __forceinline__ f32x4_t mfma16(bf16x8_t a, bf16x8_t b, f32x4_t c) {
  return __builtin_amdgcn_mfma_f32_16x16x32_bf16(a, b, c, 0, 0, 0);
}

// Relaxed agent-scope atomics (served at device coherence point; proven r2).
__device__ __forceinline__ unsigned aldc(const unsigned* p) {
  return __hip_atomic_load(p, __ATOMIC_RELAXED, __HIP_MEMORY_SCOPE_AGENT);
}
__device__ __forceinline__ unsigned long long ald64(const unsigned long long* p) {
  return __hip_atomic_load(p, __ATOMIC_RELAXED, __HIP_MEMORY_SCOPE_AGENT);
}
__device__ __forceinline__ void ast32(unsigned* p, unsigned v) {
  __hip_atomic_store(p, v, __ATOMIC_RELAXED, __HIP_MEMORY_SCOPE_AGENT);
}

// All 256 threads: poll 16 member counters (stride 32 u32 = 128B lines) until
// all >= target; returns the group min (uniform per 16-lane subgroup).
__device__ __forceinline__ unsigned wait_ge(const unsigned* base, unsigned target) {
  const int i = threadIdx.x & 15;
  unsigned v;
  while (true) {
    v = aldc(base + i * 32);
    if (__ballot(v < target) == 0ull) break;
    __builtin_amdgcn_s_sleep(2);
  }
  unsigned mn = v;
  mn = min(mn, (unsigned)__shfl_xor((int)mn, 1));
  mn = min(mn, (unsigned)__shfl_xor((int)mn, 2));
  mn = min(mn, (unsigned)__shfl_xor((int)mn, 4));
  mn = min(mn, (unsigned)__shfl_xor((int)mn, 8));
  return mn;
}

// ---------------------------------------------------------------------------
// MFMA GEMM (round-1, proven) — used only for the final FC here.
// ---------------------------------------------------------------------------
template <int K, int N, bool ASPLIT, bool OUTBF16>
__global__ __launch_bounds__(256, 2) void gemm_k(
    const void* __restrict__ Aq, const float* __restrict__ Wf,
    const float* __restrict__ bias1, const float* __restrict__ bias2,
    void* __restrict__ Cq) {
  extern __shared__ unsigned short smem[];
  unsigned short* Ahi = smem;
  unsigned short* Alo = Ahi + (ASPLIT ? 8192 : 0);
  unsigned short* Bhi = Alo + 8192;
  unsigned short* Blo = Bhi + 8192;

  const int tid = threadIdx.x;
  const int wave = tid >> 6, lane = tid & 63;
  const int wm = wave >> 1, wn = wave & 1;
  const int lm = lane & 15, lk = lane >> 4;
  const int m0 = blockIdx.y * 128, n0 = blockIdx.x * 128;

  f32x4_t acc[4][4] = {};

  for (int kc = 0; kc < K; kc += 64) {
    __syncthreads();
#pragma unroll
    for (int p = 0; p < 4; ++p) {
      int fl = p * 256 + tid;
      int row = fl & 127, ko = (fl >> 7) & 3, kit = fl >> 9;
      int kk = kc + kit * 32 + ko * 8;
      if (ASPLIT) {
        const float* src = (const float*)Aq + (size_t)(m0 + row) * K + kk;
        union { bf16x8_t s; unsigned short u[8]; } th, tl;
#pragma unroll
        for (int e = 0; e < 8; ++e) {
          float v = src[e];
          unsigned short h = f2bf(v);
          th.u[e] = (short)h;
          tl.u[e] = (short)f2bf(v - bf2f(h));
        }
        *(bf16x8_t*)(Ahi + (size_t)fl * 8) = th.s;
        *(bf16x8_t*)(Alo + (size_t)fl * 8) = tl.s;
      } else {
        const unsigned short* src = (const unsigned short*)Aq + (size_t)(m0 + row) * K + kk;
        *(bf16x8_t*)(Ahi + (size_t)fl * 8) = *(const bf16x8_t*)src;
      }
    }
#pragma unroll
    for (int p = 0; p < 4; ++p) {
      int fl = p * 256 + tid;
      int row = fl & 127, ko = (fl >> 7) & 3, kit = fl >> 9;
      int kk = kc + kit * 32 + ko * 8;
      const float* src = Wf + (size_t)(n0 + row) * K + kk;
      union { bf16x8_t s; unsigned short u[8]; } th, tl;
#pragma unroll
      for (int e = 0; e < 8; ++e) {
        float v = src[e];
        unsigned short h = f2bf(v);
        th.u[e] = (short)h;
        tl.u[e] = (short)f2bf(v - bf2f(h));
      }
      *(bf16x8_t*)(Bhi + (size_t)fl * 8) = th.s;
      *(bf16x8_t*)(Blo + (size_t)fl * 8) = tl.s;
    }
    __syncthreads();
#pragma unroll
    for (int kit = 0; kit < 2; ++kit) {
      bf16x8_t bhf[4], blf[4];
#pragma unroll
      for (int n = 0; n < 4; ++n) {
        int br = wn * 64 + n * 16 + lm;
        bhf[n] = *(const bf16x8_t*)(Bhi + ((size_t)(kit * 4 + lk) * 128 + br) * 8);
        blf[n] = *(const bf16x8_t*)(Blo + ((size_t)(kit * 4 + lk) * 128 + br) * 8);
      }
#pragma unroll
      for (int m = 0; m < 4; ++m) {
        int ar = wm * 64 + m * 16 + lm;
        bf16x8_t a = *(const bf16x8_t*)(Ahi + ((size_t)(kit * 4 + lk) * 128 + ar) * 8);
        bf16x8_t al;
        if (ASPLIT) al = *(const bf16x8_t*)(Alo + ((size_t)(kit * 4 + lk) * 128 + ar) * 8);
#pragma unroll
        for (int n = 0; n < 4; ++n) {
          acc[m][n] = mfma16(a, bhf[n], acc[m][n]);
          acc[m][n] = mfma16(a, blf[n], acc[m][n]);
          if (ASPLIT) acc[m][n] = mfma16(al, bhf[n], acc[m][n]);
        }
      }
    }
  }
#pragma unroll
  for (int n = 0; n < 4; ++n) {
    int col = n0 + wn * 64 + n * 16 + lm;
    float bv = bias1[col];
    if (bias2 != nullptr) bv += bias2[col];
#pragma unroll
    for (int m = 0; m < 4; ++m) {
#pragma unroll
      for (int r = 0; r < 4; ++r) {
        int row = m0 + wm * 64 + m * 16 + lk * 4 + r;
        float v = acc[m][n][r] + bv;
        if (OUTBF16)
          ((unsigned short*)Cq)[(size_t)row * N + col] = f2bf(v);
        else
          ((float*)Cq)[(size_t)row * N + col] = v;
      }
    }
  }
}

// x pre-split: fp32 -> (hi, lo) bf16 planes.
__global__ __launch_bounds__(256) void splitx_k(const float* __restrict__ x,
                                               unsigned short* __restrict__ xhi,
                                               unsigned short* __restrict__ xlo) {
  int i = (blockIdx.x * 256 + threadIdx.x) * 4;
  float4 v = *(const float4*)(x + i);
  ushort4 h, lo;
  h.x = f2bf(v.x); lo.x = f2bf(v.x - bf2f(h.x));
  h.y = f2bf(v.y); lo.y = f2bf(v.y - bf2f(h.y));
  h.z = f2bf(v.z); lo.z = f2bf(v.z - bf2f(h.z));
  h.w = f2bf(v.w); lo.w = f2bf(v.w - bf2f(h.w));
  *(ushort4*)(xhi + i) = h;
  *(ushort4*)(xlo + i) = lo;
}

// ---------------------------------------------------------------------------
// Persistent pipelined RNN (round-2 geometry): 256 blocks, block = (l = bid>>6,
// me = (bid&63)>>2, bg = bid&3); 64 neurons x 16 batches per block; group
// (l,bg) = 16 member blocks. h ring bf16-hi only, [k/8][b][k%8] frag order.
// Progress: per-block counter (own 128B line), relaxed sc1 store of t+2 after
// step t (preceded by __syncthreads, which drains vmcnt -> release semantics);
// init stores 1. Polls: 16-wide ballot over member lines.
// ---------------------------------------------------------------------------
__global__ __launch_bounds__(256, 1) void rnn_k(
    const float* __restrict__ hidden,
    const float* __restrict__ Wih0, const float* __restrict__ Whh0,
    const float* __restrict__ bih0, const float* __restrict__ bhh0,
    const float* __restrict__ WihL, const float* __restrict__ WhhL,
    const float* __restrict__ bihL, const float* __restrict__ bhhL,
    const unsigned short* __restrict__ xhi, const unsigned short* __restrict__ xlo,
    unsigned short* __restrict__ ring, unsigned short* __restrict__ seqr,
    unsigned short* __restrict__ s3, float* __restrict__ hn,
    unsigned* __restrict__ prog) {
  extern __shared__ char lds[];  // 64 KB: h 32K | seq 32K
  char* ldsH = lds;
  char* ldsS = lds + 32768;
  const int tid = threadIdx.x;
  const int wave = tid >> 6, lane = tid & 63;
  const int lm = lane & 15, lk = lane >> 4;
  const int bid = blockIdx.x;
  const int l = bid >> 6;
  const int sub = bid & 63;
  const int me = sub >> 2, bg = sub & 3;
  const int g = l * 4 + bg;
  const int j0 = me * 64 + wave * 16;
  const int j = j0 + lm;

  // ---- weight fragments (bf16-hi) in registers
  const float* Whh = (l == 0) ? Whh0 : WhhL + (size_t)(l - 1) * H_ * H_;
  bf16x8_t bh[32];
#pragma unroll
  for (int kit = 0; kit < 32; ++kit) {
    const float* src = Whh + (size_t)j * H_ + kit * 32 + lk * 8;
    union { bf16x8_t s; unsigned short u[8]; } th;
#pragma unroll
    for (int e = 0; e < 8; ++e) th.u[e] = (short)f2bf(src[e]);
    bh[kit] = th.s;
  }
  bf16x8_t bw[32];
  bf16x8_t w0h[4], w0l[4];
  if (l > 0) {
    const float* Wih = WihL + (size_t)(l - 1) * H_ * H_;
#pragma unroll
    for (int kit = 0; kit < 32; ++kit) {
      const float* src = Wih + (size_t)j * H_ + kit * 32 + lk * 8;
      union { bf16x8_t s; unsigned short u[8]; } th;
#pragma unroll
      for (int e = 0; e < 8; ++e) th.u[e] = (short)f2bf(src[e]);
      bw[kit] = th.s;
    }
  } else {
#pragma unroll
    for (int kit = 0; kit < 4; ++kit) {
      const float* src = Wih0 + (size_t)j * I_ + kit * 32 + lk * 8;
      union { bf16x8_t s; unsigned short u[8]; } th, tl;
#pragma unroll
      for (int e = 0; e < 8; ++e) {
        float v = src[e];
        unsigned short h = f2bf(v);
        th.u[e] = (short)h;
        tl.u[e] = (short)f2bf(v - bf2f(h));
      }
      w0h[kit] = th.s; w0l[kit] = tl.s;
    }
  }
  float bias = (l == 0) ? (bih0[j] + bhh0[j])
                        : (bihL[(size_t)(l - 1) * H_ + j] + bhhL[(size_t)(l - 1) * H_ + j]);

  // ---- init: h0 -> ring slot 1 (this block's 64-neuron portion, u32-packed)
  {
    unsigned* r1 = (unsigned*)(ring + ((size_t)(l * 2 + 1) * 4 + bg) * 16384);
#pragma unroll
    for (int q = 0; q < 2; ++q) {
      int s = q * 256 + tid;  // [0,512) -> u32 idx me*512 + s
      int J = s >> 6, b16 = (s >> 2) & 15, h4 = s & 3;
      int jj = me * 64 + J * 8 + h4 * 2;
      const float* hp = hidden + (size_t)l * B_ * H_ + (bg * 16 + b16) * H_ + jj;
      unsigned p0 = f2bf(hp[0]), p1 = f2bf(hp[1]);
      ast32(r1 + me * 512 + s, p0 | (p1 << 16));
    }
  }
  __syncthreads();  // drains vmcnt for the whole block
  if (tid == 0) ast32(prog + (size_t)(g * 16 + me) * 32, 1u);

  const unsigned* ownB = prog + (size_t)g * 512;
  const unsigned* upB = prog + (size_t)((l - 1) * 4 + bg) * 512;  // l>0 only
  const unsigned* dnB = prog + (size_t)((l + 1) * 4 + bg) * 512;  // l<3 only
  unsigned upMin = 1, dnMin = 1;

  for (int t = 0; t < T_; ++t) {
    // A. upstream wait (cached) + seq prefetch (guarded only by upstream)
    unsigned long long stmp[16];
    if (l > 0) {
      if (upMin < (unsigned)(t + 2)) upMin = wait_ge(upB, (unsigned)(t + 2));
      asm volatile("" ::: "memory");
      const unsigned long long* sp = (const unsigned long long*)(seqr +
          ((size_t)((l - 1) * D_ + (t & (D_ - 1))) * 4 + bg) * 16384);
#pragma unroll
      for (int i = 0; i < 16; ++i) stmp[i] = ald64(sp + i * 256 + tid);
    }
    // B. downstream back-pressure before overwriting seq slot (cached)
    if (l < 3 && t >= D_) {
      if (dnMin < (unsigned)(t - D_ + 2)) dnMin = wait_ge(dnB, (unsigned)(t - D_ + 2));
    }
    // C. own-group barrier: peers finished step t-1
    wait_ge(ownB, (unsigned)(t + 1));
    asm volatile("" ::: "memory");
    // D. h slice loads (32 KB bf16-hi)
    unsigned long long htmp[16];
    const unsigned long long* hp = (const unsigned long long*)(ring +
        ((size_t)(l * 2 + ((t & 1) ^ 1)) * 4 + bg) * 16384);
#pragma unroll
    for (int i = 0; i < 16; ++i) htmp[i] = ald64(hp + i * 256 + tid);
    // E. stage to LDS (frag order preserved)
    {
      unsigned long long* dh = (unsigned long long*)ldsH;
#pragma unroll
      for (int i = 0; i < 16; ++i) dh[i * 256 + tid] = htmp[i];
      if (l > 0) {
        unsigned long long* dsp = (unsigned long long*)ldsS;
#pragma unroll
        for (int i = 0; i < 16; ++i) dsp[i * 256 + tid] = stmp[i];
      }
    }
    __syncthreads();
    // F. MFMA: a0 = h @ Whh^T, a3 = xin
    f32x4_t a0 = {0.f, 0.f, 0.f, 0.f}, a3 = {0.f, 0.f, 0.f, 0.f};
    if (l > 0) {
#pragma unroll
      for (int kit = 0; kit < 32; ++kit) {
        const int fo = ((kit * 4 + lk) * 16 + lm) * 16;
        bf16x8_t ah = *(const bf16x8_t*)(ldsH + fo);
        bf16x8_t as = *(const bf16x8_t*)(ldsS + fo);
        a0 = mfma16(ah, bh[kit], a0);
        a3 = mfma16(as, bw[kit], a3);
      }
    } else {
#pragma unroll
      for (int kit = 0; kit < 32; ++kit) {
        const int fo = ((kit * 4 + lk) * 16 + lm) * 16;
        bf16x8_t ah = *(const bf16x8_t*)(ldsH + fo);
        a0 = mfma16(ah, bh[kit], a0);
      }
      const int b = bg * 16 + lm;
#pragma unroll
      for (int kit = 0; kit < 4; ++kit) {
        const size_t xo = ((size_t)b * T_ + t) * I_ + kit * 32 + lk * 8;
        bf16x8_t xh = *(const bf16x8_t*)(xhi + xo);
        bf16x8_t xl = *(const bf16x8_t*)(xlo + xo);
        a3 = mfma16(xh, w0h[kit], a3);
        a3 = mfma16(xl, w0h[kit], a3);
        a3 = mfma16(xh, w0l[kit], a3);
      }
    }
    // G. epilogue: lane holds (j, b = bg*16 + lk*4 + r); u32 pair-packed stores
    unsigned* rwu = (unsigned*)(ring + ((size_t)(l * 2 + (t & 1)) * 4 + bg) * 16384);
    unsigned* swu = (unsigned*)(seqr + ((size_t)(l * D_ + (t & (D_ - 1))) * 4 + bg) * 16384);
#pragma unroll
    for (int r = 0; r < 4; ++r) {
      const int b15 = lk * 4 + r;
      float v = a0[r] + a3[r] + bias;
      v = fmaxf(v, 0.f);
      unsigned hi = f2bf(v);
      unsigned other = (unsigned)__shfl_xor((int)hi, 1);
      if (!(lm & 1)) {
        const unsigned pk = hi | (other << 16);
        const int p32 = ((j >> 3) * 16 + b15) * 4 + ((j & 7) >> 1);
        ast32(rwu + p32, pk);
        if (l < 3) ast32(swu + p32, pk);
      }
      if (l == 3) s3[((size_t)(bg * 16 + b15) * T_ + t) * H_ + j] = (unsigned short)hi;
      if (t == T_ - 1) hn[(size_t)l * B_ * H_ + (bg * 16 + b15) * H_ + j] = v;
    }
    // H. release: __syncthreads drains all waves' vmcnt, then publish progress
    __syncthreads();
    if (tid == 0) ast32(prog + (size_t)(g * 16 + me) * 32, (unsigned)(t + 2));
  }
}

// ---------------------------------------------------------------------------
// ws layout: prog 32KB (16 groups x 16 members x 128B) | pad to 64K |
// ring 1MB (u16 [l][slot2][bg][16384]) | seqr 12MB | s3 64MB | xhi 8MB |
// xlo 8MB  => ~93 MB.
// ---------------------------------------------------------------------------
extern "C" void kernel_launch(void* const* d_in, const int* in_sizes, int n_in,
                              void* d_out, int out_size, void* d_ws, size_t ws_size,
                              hipStream_t stream) {
  const float* x = (const float*)d_in[0];
  const float* hidden = (const float*)d_in[1];
  const float* Wih0 = (const float*)d_in[2];
  const float* Whh0 = (const float*)d_in[3];
  const float* bih0 = (const float*)d_in[4];
  const float* bhh0 = (const float*)d_in[5];
  const float* WihL = (const float*)d_in[6];
  const float* WhhL = (const float*)d_in[7];
  const float* bihL = (const float*)d_in[8];
  const float* bhhL = (const float*)d_in[9];
  const float* Wfc = (const float*)d_in[10];
  const float* bfc = (const float*)d_in[11];
  float* out = (float*)d_out;
  float* hn = out + (size_t)M_ * O_;

  char* ws = (char*)d_ws;
  unsigned* prog = (unsigned*)ws;
  unsigned short* ring = (unsigned short*)(ws + 65536);
  unsigned short* seqr = (unsigned short*)(ws + 65536 + (1u << 20));
  unsigned short* s3 = (unsigned short*)(ws + 65536 + (1u << 20) + (12u << 20));
  unsigned short* xhi = (unsigned short*)(ws + 65536 + (1u << 20) + (12u << 20) + (64u << 20));
  unsigned short* xlo = xhi + (size_t)B_ * T_ * I_;

  hipMemsetAsync(ws, 0, 65536, stream);  // progress counters
  splitx_k<<<(B_ * T_ * I_) / 1024, 256, 0, stream>>>(x, xhi, xlo);

  hipFuncSetAttribute((const void*)rnn_k, hipFuncAttributeMaxDynamicSharedMemorySize,
                      64 * 1024);
  rnn_k<<<256, 256, 64 * 1024, stream>>>(hidden, Wih0, Whh0, bih0, bhh0,
                                         WihL, WhhL, bihL, bhhL, xhi, xlo,
                                         ring, seqr, s3, hn, prog);

  gemm_k<H_, O_, false, false><<<dim3(O_ / 128, M_ / 128), 256, 48 * 1024, stream>>>(
      (const void*)s3, Wfc, bfc, nullptr, (void*)out);
}